// Round 3
// baseline (120.862 us; speedup 1.0000x reference)
//
#include <hip/hip_runtime.h>
#include <math.h>

// WignerDRotation: out = Z(alpha) * J * Z(beta) * J * Z(gamma) * x, block-diagonal
// over irreps [0]*256 + [1]*256 + [2]*128 + [3]*64, DIM=2112, CH=32, N=1024.
// All copies of the same l share one d x d composite matrix M_l per batch row.
//
// Round-3 structure: (1) build_M writes per-batch 3x3/5x5/7x7 composites to d_ws;
// (2) stream kernel stages copy-aligned chunks into LDS via global_load_lds
// (width 16, perfectly coalesced 1 KiB/wave-instruction on BOTH load and store
// sides — identical global pattern to a pure copy), applies M via LDS gathers,
// stores linearly. This removes the 8x128B-scattered-segment pattern of rounds
// 1-2, the last structural difference from the 6.3 TB/s copy roofline.

namespace {

typedef float f4 __attribute__((ext_vector_type(4)));

constexpr float SQ3_2 = 0.86602540378443864676f;  // sqrt(3)/2
constexpr float S6    = 0.61237243569579452455f;  // sqrt(6)/4
constexpr float S10   = 0.79056941504209483300f;  // sqrt(10)/4
constexpr float S15   = 0.96824583655185422129f;  // sqrt(15)/4

// J_l: real-SH matrix of the y<->z axis swap (Condon-Shortley phase, rows/cols
// ordered m = -l..l). J = J^T = J^-1.
template<int L> struct JM;
template<> struct JM<1> {
  static constexpr float v[3][3] = {
    { 0.f, -1.f, 0.f},
    {-1.f,  0.f, 0.f},
    { 0.f,  0.f, 1.f}};
};
template<> struct JM<2> {
  static constexpr float v[5][5] = {
    { 0.f, 0.f,  0.f,   -1.f,  0.f},
    { 0.f, 1.f,  0.f,    0.f,  0.f},
    { 0.f, 0.f, -0.5f,   0.f, -SQ3_2},
    {-1.f, 0.f,  0.f,    0.f,  0.f},
    { 0.f, 0.f, -SQ3_2,  0.f,  0.5f}};
};
template<> struct JM<3> {
  static constexpr float v[7][7] = {
    { 0.f, 0.f, 0.f, S10,  0.f,   -S6,  0.f},
    { 0.f, 1.f, 0.f, 0.f,  0.f,    0.f, 0.f},
    { 0.f, 0.f, 0.f, S6,   0.f,    S10, 0.f},
    { S10, 0.f, S6,  0.f,  0.f,    0.f, 0.f},
    { 0.f, 0.f, 0.f, 0.f, -0.25f,  0.f, -S15},
    {-S6,  0.f, S10, 0.f,  0.f,    0.f, 0.f},
    { 0.f, 0.f, 0.f, 0.f, -S15,    0.f, 0.25f}};
};

// Column q of M_l = Zalpha * J * Zbeta * J * Zgamma. Column-local: Z only mixes
// m <-> -m inside a column, so each lane computes one column independently.
template<int L>
__device__ inline void compute_M_col(int q, float al, float be, float ga, float* M) {
  constexpr int D = 2 * L + 1;
  const int mq = q - L;
  float sg, cg;
  sincosf((float)mq * ga, &sg, &cg);
  float v[D];
#pragma unroll
  for (int p = 0; p < D; ++p)
    v[p] = cg * JM<L>::v[p][q] + sg * JM<L>::v[p][(D - 1) - q];
  float c1, s1;
  sincosf(be, &s1, &c1);
  float cb[L + 1], sb[L + 1];
  cb[0] = 1.f; sb[0] = 0.f;
  cb[1] = c1;  sb[1] = s1;
#pragma unroll
  for (int k = 2; k <= L; ++k) {
    cb[k] = 2.f * c1 * cb[k - 1] - cb[k - 2];
    sb[k] = 2.f * c1 * sb[k - 1] - sb[k - 2];
  }
  float w[D];
#pragma unroll
  for (int p = 0; p < D; ++p) {
    const int mp = p - L;
    const int am = mp < 0 ? -mp : mp;
    const float c = cb[am];
    const float s = mp < 0 ? -sb[am] : sb[am];
    w[p] = c * v[p] - s * v[(D - 1) - p];
  }
  float u[D];
#pragma unroll
  for (int p = 0; p < D; ++p) {
    float acc = 0.f;
#pragma unroll
    for (int r = 0; r < D; ++r) acc = fmaf(JM<L>::v[p][r], w[r], acc);
    u[p] = acc;
  }
  sincosf(al, &s1, &c1);
  float ca[L + 1], sa[L + 1];
  ca[0] = 1.f; sa[0] = 0.f;
  ca[1] = c1;  sa[1] = s1;
#pragma unroll
  for (int k = 2; k <= L; ++k) {
    ca[k] = 2.f * c1 * ca[k - 1] - ca[k - 2];
    sa[k] = 2.f * c1 * sa[k - 1] - sa[k - 2];
  }
#pragma unroll
  for (int p = 0; p < D; ++p) {
    const int mp = p - L;
    const int am = mp < 0 ? -mp : mp;
    const float c = ca[am];
    const float s = mp < 0 ? -sa[am] : sa[am];
    M[p * D + q] = c * u[p] - s * u[(D - 1) - p];
  }
}

// ws layout per batch row n (96 floats): M3(7x7)@0..48, M2(5x5)@49..73, M1(3x3)@74..82.
__global__ __launch_bounds__(256) void build_M_kernel(
    const float* __restrict__ alpha, const float* __restrict__ beta,
    const float* __restrict__ gamma, float* __restrict__ ws, int n_batch) {
  const int t = threadIdx.x;
  const int n = blockIdx.x * 16 + (t >> 4);
  const int col = t & 15;
  if (n >= n_batch || col >= 15) return;
  const float al = alpha[n], be = beta[n], ga = gamma[n];
  float* w = ws + (size_t)n * 96;
  if (col < 7)       compute_M_col<3>(col,      al, be, ga, w);
  else if (col < 12) compute_M_col<2>(col - 7,  al, be, ga, w + 49);
  else               compute_M_col<1>(col - 12, al, be, ga, w + 74);
}

// Async global->LDS, 16 B per lane. Our LDS layout is linear in lane order,
// exactly the wave-uniform-base + lane*16 pattern the HW writes.
__device__ inline void gload16(const void* g, void* l) {
  __builtin_amdgcn_global_load_lds(
      (const __attribute__((address_space(1))) void*)g,
      (__attribute__((address_space(3))) void*)l, 16, 0, 0);
}

// One section of irreps of dimension D: NCHUNK chunks of CHUNK_ROWS rows
// (copy-aligned). Load chunk coalesced into LDS, barrier, compute output
// element k = sum_q M[p][q] * buf[k + (q-p)*8] (p = row%D), store coalesced.
template<int D, int CHUNK_ROWS, int NCHUNK>
__device__ inline void apply_section(const f4* __restrict__ inSec,
                                     f4* __restrict__ outSec,
                                     const float* __restrict__ M,  // LDS, D*D
                                     f4* __restrict__ buf, int t) {
  constexpr int F = CHUNK_ROWS * 8;            // f4 per chunk
  constexpr int ITER = (F + 511) / 512;
  for (int c = 0; c < NCHUNK; ++c) {
    const f4* src = inSec + c * F;
#pragma unroll
    for (int i = 0; i < ITER; ++i) {
      const int k = t + 512 * i;               // guard is wave-uniform (F%64==0)
      if (k < F) gload16(src + k, buf + k);
    }
    __syncthreads();
    f4* dst = outSec + c * F;
#pragma unroll
    for (int i = 0; i < ITER; ++i) {
      const int k = t + 512 * i;
      if (k < F) {
        const int r = k >> 3;                  // row within chunk
        const int p = r % D;                   // row within copy
        const float* Mrow = M + p * D;
        const f4* b = buf + (k - p * 8);       // copy's row-0 element, same ch
        f4 a = Mrow[0] * b[0];
#pragma unroll
        for (int q = 1; q < D; ++q) a += Mrow[q] * b[q * 8];
        dst[k] = a;
      }
    }
    __syncthreads();
  }
}

// 512 threads, one batch row per block. LDS 29 KB -> 4 blocks/CU.
__global__ __launch_bounds__(512, 4) void wigner_stream_kernel(
    const float* __restrict__ in, const float* __restrict__ ws,
    float* __restrict__ out) {
  __shared__ f4 buf[1792];   // max chunk: l=3, 224 rows = 28 KB
  __shared__ float M[96];
  const int n = blockIdx.x;
  const int t = threadIdx.x;
  if (t < 83) M[t] = ws[(size_t)n * 96 + t];   // published by first chunk barrier

  const size_t base = (size_t)n * (2112 * 8);  // f4 units
  const f4* inN = (const f4*)in + base;
  f4* outN = (f4*)out + base;

  // l=0 (rows 0..255): identity copy, already pure-copy pattern.
#pragma unroll
  for (int i = 0; i < 4; ++i) outN[t + 512 * i] = inN[t + 512 * i];

  // l=1: 256 copies (rows 256..1023): 4 chunks x 64 copies (192 rows, 24 KB)
  apply_section<3, 192, 4>(inN + 256 * 8, outN + 256 * 8, M + 74, buf, t);
  // l=2: 128 copies (rows 1024..1663): 4 chunks x 32 copies (160 rows, 20 KB)
  apply_section<5, 160, 4>(inN + 1024 * 8, outN + 1024 * 8, M + 49, buf, t);
  // l=3: 64 copies (rows 1664..2111): 2 chunks x 32 copies (224 rows, 28 KB)
  apply_section<7, 224, 2>(inN + 1664 * 8, outN + 1664 * 8, M, buf, t);
}

}  // namespace

extern "C" void kernel_launch(void* const* d_in, const int* in_sizes, int n_in,
                              void* d_out, int out_size, void* d_ws, size_t ws_size,
                              hipStream_t stream) {
  const float* in    = (const float*)d_in[0];
  const float* alpha = (const float*)d_in[1];
  const float* beta  = (const float*)d_in[2];
  const float* gamma = (const float*)d_in[3];
  float* out = (float*)d_out;
  const int n_batch = in_sizes[1];  // 1024

  float* ws = (float*)d_ws;
  build_M_kernel<<<(n_batch + 15) / 16, 256, 0, stream>>>(alpha, beta, gamma,
                                                          ws, n_batch);
  wigner_stream_kernel<<<n_batch, 512, 0, stream>>>(in, ws, out);
}